// Round 7
// baseline (256.705 us; speedup 1.0000x reference)
//
#include <hip/hip_runtime.h>
#include <math.h>

// CIN (xDeepFM) — split-bf16, 32x32x16 MFMA, barrier-free per-wave pipeline.
// y[b,o,d] = bias[o] + sum_f x[b,f,d] * ( sum_h W[o,f*H+h] * h_in[b,h,d] )
// Inner sum: 32x32x16 bf16 MFMA, W,h split hi+lo bf16 (3 terms, lo*lo dropped).
// Block = 1 batch, 4 waves; wave w owns o-rows [32w,32w+32) x all 64 d.
// Chunk = K=32 slice (16 KB: [plane(hi/lo) x kstep16][mt][lane]x16B); wave w
// stages and reads ONLY its mt-stripe -> no barriers in the hot loop, only
// per-wave counted vmcnt(4). LDS: 2x16KB chunk dbuf + 8KB x-tile.
// B=512, F=32, D=64, O=128; H0=32 (h=x), H1=H2=128.

typedef __attribute__((ext_vector_type(8)))  short bf16x8;
typedef __attribute__((ext_vector_type(4)))  float f32x4;
typedef __attribute__((ext_vector_type(16))) float f32x16;
typedef __attribute__((ext_vector_type(4)))  unsigned short u16x4;

#define HT_LO 4194304   // shorts: 512*64*128 (offset of lo plane)

__device__ __forceinline__ unsigned short f2bf(float f) {
  unsigned int u = __float_as_uint(f);
  u = (u + 0x7fffu + ((u >> 16) & 1u)) >> 16;   // RNE
  return (unsigned short)u;
}
__device__ __forceinline__ float bf2f(unsigned short h) {
  return __uint_as_float((unsigned int)h << 16);
}

__device__ __forceinline__ void gll16(const void* g, void* l) {
  __builtin_amdgcn_global_load_lds(
      (const __attribute__((address_space(1))) unsigned int*)g,
      (__attribute__((address_space(3))) unsigned int*)l, 16, 0, 0);
}

// ---- pre-pass: repack W (fp32, row-major 128xK) into split-bf16 chunk image.
// unit t (16B): chunk c = t>>10; round r = (t>>8)&3; idx = t&255 (mt=idx>>6, l=idx&63)
// c -> pass = c/(32*KCH); f = (c%(32*KCH))/KCH; ksc = c%KCH.  plane s=r>>1, ks=r&1.
// element: W[o = mt*32+(l&31)][kcol = f*H + pass*KCH*32 + ksc*32 + ks*16 + (l>>5)*8 + j]
__global__ void repack_w_kernel(const float* __restrict__ W, unsigned short* __restrict__ dst,
                                int H, int KCH, int nunits)
{
  const int t = blockIdx.x * 256 + threadIdx.x;
  if (t >= nunits) return;
  const int K = 32 * H;
  const int c = t >> 10;
  const int r = (t >> 8) & 3;
  const int idx = t & 255;
  const int mt = idx >> 6, l = idx & 63;
  const int NCPP = 32 * KCH;
  const int pass = c / NCPP, rem = c % NCPP;
  const int f = rem / KCH, ksc = rem % KCH;
  const int s = r >> 1, ks = r & 1;
  const int o = mt * 32 + (l & 31);
  const int kcol = f * H + pass * (KCH * 32) + ksc * 32 + ks * 16 + (l >> 5) * 8;
  const float* src = W + (size_t)o * K + kcol;
  u16x4 a, bq;
#pragma unroll
  for (int j = 0; j < 4; ++j) {
    float v = src[j];
    unsigned short hb = f2bf(v);
    a[j] = s ? f2bf(v - bf2f(hb)) : hb;
    v = src[4 + j];
    hb = f2bf(v);
    bq[j] = s ? f2bf(v - bf2f(hb)) : hb;
  }
  *(u16x4*)(dst + (size_t)t * 8)     = a;
  *(u16x4*)(dst + (size_t)t * 8 + 4) = bq;
}

// ---- main layer kernel ----
template<int H, int NPASS, int KCH, bool FIRST, bool STORE_H>
__global__ __launch_bounds__(256) void cin_mfma_layer(
    const unsigned short* __restrict__ Wimg,
    const float* __restrict__ x,               // (B,32,64) fp32
    const unsigned short* __restrict__ hTin,   // hi plane; lo at +HT_LO (null if FIRST)
    const float* __restrict__ bias,
    unsigned short* __restrict__ hTout,        // hi plane; lo at +HT_LO
    float* __restrict__ outs, int col_off)
{
  constexpr int NCPP = 32 * KCH;               // chunks per pass
  constexpr int KPP  = 2 * KCH;                // K16-steps per pass
  __shared__ char lds[40960];
  const int tid = threadIdx.x;
  const int w = tid >> 6, l = tid & 63, lo5 = l & 31, hi = l >> 5;
  const int b = blockIdx.x;
  const int obase = w * 32;
  const float* lx = (const float*)(lds + 32768);

  // prologue: stage x (8KB) + chunk 0 (16KB), lane-linear
#pragma unroll
  for (int r = 0; r < 2; ++r)
    gll16(x + (size_t)b * 2048 + (r * 256 + tid) * 4, lds + 32768 + r * 4096 + w * 1024);
#pragma unroll
  for (int r = 0; r < 4; ++r)
    gll16((const char*)Wimg + (size_t)(r * 256 + tid) * 16, lds + r * 4096 + w * 1024);

  f32x16 Y[2] = {};
  const f32x16 Z = {};
  bf16x8 Bh[KPP][2], Bl[KPP][2];

  asm volatile("s_waitcnt vmcnt(0)" ::: "memory");
  __builtin_amdgcn_s_barrier();   // the ONLY barrier: publishes the x-tile

  if constexpr (FIRST) {
    // build split B-fragments from raw x in LDS (h == x; KPP == 2)
#pragma unroll
    for (int kk = 0; kk < 2; ++kk)
#pragma unroll
      for (int nt = 0; nt < 2; ++nt) {
        union { bf16x8 v; unsigned short u[8]; } th, tl;
#pragma unroll
        for (int j = 0; j < 8; ++j) {
          const float xv = lx[(kk * 16 + hi * 8 + j) * 64 + nt * 32 + lo5];
          const unsigned short hb = f2bf(xv);
          th.u[j] = hb; tl.u[j] = f2bf(xv - bf2f(hb));
        }
        Bh[kk][nt] = th.v; Bl[kk][nt] = tl.v;
      }
  }

#pragma unroll 1
  for (int pass = 0; pass < NPASS; ++pass) {
    if constexpr (!FIRST) {
      // B-fragments for this pass (reused across all 32 f)
#pragma unroll
      for (int kk = 0; kk < KPP; ++kk)
#pragma unroll
        for (int nt = 0; nt < 2; ++nt) {
          const size_t off = (size_t)b * 8192 + (size_t)(nt * 32 + lo5) * 128
                           + pass * (KCH * 32) + kk * 16 + hi * 8;
          Bh[kk][nt] = *(const bf16x8*)(hTin + off);
          Bl[kk][nt] = *(const bf16x8*)(hTin + HT_LO + off);
        }
    }
    const char* wbase = (const char*)Wimg + (size_t)pass * NCPP * 16384;
#pragma unroll 1
    for (int fo = 0; fo < 32; fo += 4) {
#pragma unroll
      for (int fi = 0; fi < 4; ++fi) {
        const int f = fo + fi;
        f32x16 G[2];
#pragma unroll
        for (int ksc = 0; ksc < KCH; ++ksc) {
          const int par = (KCH == 1) ? (fi & 1) : (ksc & 1);   // global chunk parity (static)
          // prefetch next chunk into other buffer (reads +16KB past image at the
          // very end — backed by the next ws region, value never consumed)
          const char* src = wbase + ((size_t)(f * KCH + ksc + 1)) * 16384;
#pragma unroll
          for (int r = 0; r < 4; ++r)
            gll16(src + (size_t)(r * 256 + tid) * 16,
                  lds + (par ^ 1) * 16384 + r * 4096 + w * 1024);
          asm volatile("s_waitcnt vmcnt(4)" ::: "memory");   // this chunk landed

          const char* bufb = lds + par * 16384 + w * 1024 + (size_t)l * 16;
          const bf16x8 Ah0 = *(const bf16x8*)(bufb + 0 * 4096);  // plane hi, ks 0
          const bf16x8 Ah1 = *(const bf16x8*)(bufb + 1 * 4096);  // plane hi, ks 1
          const bf16x8 Al0 = *(const bf16x8*)(bufb + 2 * 4096);  // plane lo, ks 0
          const bf16x8 Al1 = *(const bf16x8*)(bufb + 3 * 4096);  // plane lo, ks 1
          const int k0 = ksc * 2, k1 = ksc * 2 + 1;

          __builtin_amdgcn_s_setprio(1);
          G[0] = __builtin_amdgcn_mfma_f32_32x32x16_bf16(Ah0, Bh[k0][0], (ksc == 0) ? Z : G[0], 0, 0, 0);
          G[1] = __builtin_amdgcn_mfma_f32_32x32x16_bf16(Ah0, Bh[k0][1], (ksc == 0) ? Z : G[1], 0, 0, 0);
          G[0] = __builtin_amdgcn_mfma_f32_32x32x16_bf16(Ah0, Bl[k0][0], G[0], 0, 0, 0);
          G[1] = __builtin_amdgcn_mfma_f32_32x32x16_bf16(Ah0, Bl[k0][1], G[1], 0, 0, 0);
          G[0] = __builtin_amdgcn_mfma_f32_32x32x16_bf16(Al0, Bh[k0][0], G[0], 0, 0, 0);
          G[1] = __builtin_amdgcn_mfma_f32_32x32x16_bf16(Al0, Bh[k0][1], G[1], 0, 0, 0);
          G[0] = __builtin_amdgcn_mfma_f32_32x32x16_bf16(Ah1, Bh[k1][0], G[0], 0, 0, 0);
          G[1] = __builtin_amdgcn_mfma_f32_32x32x16_bf16(Ah1, Bh[k1][1], G[1], 0, 0, 0);
          G[0] = __builtin_amdgcn_mfma_f32_32x32x16_bf16(Ah1, Bl[k1][0], G[0], 0, 0, 0);
          G[1] = __builtin_amdgcn_mfma_f32_32x32x16_bf16(Ah1, Bl[k1][1], G[1], 0, 0, 0);
          G[0] = __builtin_amdgcn_mfma_f32_32x32x16_bf16(Al1, Bh[k1][0], G[0], 0, 0, 0);
          G[1] = __builtin_amdgcn_mfma_f32_32x32x16_bf16(Al1, Bh[k1][1], G[1], 0, 0, 0);
          __builtin_amdgcn_s_setprio(0);
        }
        const float s0 = lx[f * 64 + lo5];        // x[b][f][col], col = lane&31
        const float s1 = lx[f * 64 + 32 + lo5];
#pragma unroll
        for (int q = 0; q < 16; ++q) {
          Y[0][q] = fmaf(G[0][q], s0, Y[0][q]);
          Y[1][q] = fmaf(G[1][q], s1, Y[1][q]);
        }
      }
    }
  }

  // ---- epilogue ----
  // C/D layout: reg r -> row = (r&3) + 8*(r>>2) + 4*hi, col = lane&31
#pragma unroll
  for (int q = 0; q < 4; ++q) {
    const f32x4 bq = *(const f32x4*)(bias + obase + q * 8 + hi * 4);
#pragma unroll
    for (int j = 0; j < 4; ++j) { Y[0][q * 4 + j] += bq[j]; Y[1][q * 4 + j] += bq[j]; }
  }

  if constexpr (STORE_H) {
#pragma unroll
    for (int nt = 0; nt < 2; ++nt) {
      const int d = nt * 32 + lo5;
#pragma unroll
      for (int q = 0; q < 4; ++q) {
        u16x4 ph, pl4;
#pragma unroll
        for (int j = 0; j < 4; ++j) {
          const float v = Y[nt][q * 4 + j];
          const unsigned short hb = f2bf(v);
          ph[j] = hb; pl4[j] = f2bf(v - bf2f(hb));
        }
        const size_t off = (size_t)b * 8192 + (size_t)d * 128 + obase + q * 8 + hi * 4;
        *(u16x4*)(hTout + off)         = ph;
        *(u16x4*)(hTout + HT_LO + off) = pl4;
      }
    }
  }

  {
    f32x16 S;
#pragma unroll
    for (int q = 0; q < 16; ++q) S[q] = Y[0][q] + Y[1][q];
#pragma unroll
    for (int m = 1; m < 32; m <<= 1)
#pragma unroll
      for (int q = 0; q < 16; ++q) S[q] += __shfl_xor(S[q], m, 64);
    if (lo5 == 0) {
#pragma unroll
      for (int q = 0; q < 4; ++q) {
        f32x4 v4 = { S[q * 4 + 0], S[q * 4 + 1], S[q * 4 + 2], S[q * 4 + 3] };
        *(f32x4*)(outs + (size_t)b * 384 + col_off + obase + q * 8 + hi * 4) = v4;
      }
    }
  }
}

// ---- final: out[b] = sigmoid( relu(outs[b,:]) . Wout + bout ) ----
__global__ __launch_bounds__(64) void cin_final_kernel(
    const float* __restrict__ outs, const float* __restrict__ Wout,
    const float* __restrict__ bout, float* __restrict__ out)
{
  const int b = blockIdx.x;
  const int lane = threadIdx.x;
  float p = 0.f;
  for (int j = lane; j < 384; j += 64) {
    float v = outs[(size_t)b * 384 + j];
    v = v > 0.f ? v : 0.f;
    p = fmaf(v, Wout[j], p);
  }
#pragma unroll
  for (int m = 32; m; m >>= 1) p += __shfl_xor(p, m, 64);
  if (lane == 0) {
    const float t = p + bout[0];
    out[b] = 1.f / (1.f + expf(-t));
  }
}

extern "C" void kernel_launch(void* const* d_in, const int* in_sizes, int n_in,
                              void* d_out, int out_size, void* d_ws, size_t ws_size,
                              hipStream_t stream)
{
  const float* x    = (const float*)d_in[0];
  const float* W0   = (const float*)d_in[1];
  const float* b0   = (const float*)d_in[2];
  const float* W1   = (const float*)d_in[3];
  const float* b1   = (const float*)d_in[4];
  const float* W2   = (const float*)d_in[5];
  const float* b2   = (const float*)d_in[6];
  const float* Wout = (const float*)d_in[7];
  const float* bout = (const float*)d_in[8];
  float* out = (float*)d_out;

  char* ws = (char*)d_ws;
  unsigned short* hT1  = (unsigned short*)ws;                           // 16 MB (hi+lo)
  unsigned short* hT2  = (unsigned short*)(ws + (16 << 20));            // 16 MB
  unsigned short* Wi0  = (unsigned short*)(ws + (32 << 20));            // 512 KB
  unsigned short* Wi1  = (unsigned short*)(ws + (32 << 20) + (512 << 10)); // 2 MB
  unsigned short* Wi2  = (unsigned short*)(ws + (32 << 20) + (2560 << 10)); // 2 MB
  float*          outs = (float*)        (ws + (32 << 20) + (4608 << 10)); // 768 KB
  // (each image's +16KB over-read from the tail prefetch lands in the next region)

  repack_w_kernel<<<128, 256, 0, stream>>>(W0, Wi0, 32,  1, 32768);
  repack_w_kernel<<<512, 256, 0, stream>>>(W1, Wi1, 128, 2, 131072);
  repack_w_kernel<<<512, 256, 0, stream>>>(W2, Wi2, 128, 2, 131072);

  cin_mfma_layer<32,  1, 1, true,  true ><<<512, 256, 0, stream>>>(Wi0, x, nullptr, b0, hT1, outs, 0);
  cin_mfma_layer<128, 2, 2, false, true ><<<512, 256, 0, stream>>>(Wi1, x, hT1,    b1, hT2, outs, 128);
  cin_mfma_layer<128, 2, 2, false, false><<<512, 256, 0, stream>>>(Wi2, x, hT2,    b2, nullptr, outs, 256);

  cin_final_kernel<<<512, 64, 0, stream>>>(outs, Wout, bout, out);
}

// Round 8
// 199.907 us; speedup vs baseline: 1.2841x; 1.2841x over previous
//
#include <hip/hip_runtime.h>
#include <math.h>

// CIN (xDeepFM) — split-bf16 16x16x32 MFMA, barrier-free, 2 batches per block.
// y[b,o,d] = bias[o] + sum_f x[b,f,d] * ( sum_h W[o,f*H+h] * h_in[b,h,d] )
// Inner sum: 16x16x32 bf16 MFMA with W,h each split hi+lo bf16:
//   W*h ~= Whi*hhi + Whi*hlo + Wlo*hhi   (lo*lo dropped, ~2^-18 rel)
// Block = 512 thr (8 waves), handles batches b0, b0+1 — W staging/A-reads are
// batch-independent, so 2 batches double MFMA per staged byte (48 MFMA/f/wave).
// Wave w stages and reads ONLY LDS bytes [r*8192 + w*1024) of each W chunk ->
// no hot-loop barriers; per-wave counted vmcnt(SR) only. One prologue barrier
// publishes the two 8KB x-tiles. grid 256 = 1 block/CU.
// B=512, F=32, D=64, O=128; H0=32 (h=x), H1=H2=128.

typedef __attribute__((ext_vector_type(8))) short bf16x8;
typedef __attribute__((ext_vector_type(4))) float f32x4;
typedef __attribute__((ext_vector_type(4))) unsigned short u16x4;

#define HT_LO 4194304   // shorts: 512*64*128 (offset of lo plane)

__device__ __forceinline__ unsigned short f2bf(float f) {
  unsigned int u = __float_as_uint(f);
  u = (u + 0x7fffu + ((u >> 16) & 1u)) >> 16;   // RNE
  return (unsigned short)u;
}
__device__ __forceinline__ float bf2f(unsigned short h) {
  return __uint_as_float((unsigned int)h << 16);
}

__device__ __forceinline__ void gll16(const void* g, void* l) {
  __builtin_amdgcn_global_load_lds(
      (const __attribute__((address_space(1))) unsigned int*)g,
      (__attribute__((address_space(3))) unsigned int*)l, 16, 0, 0);
}

// ---- pre-pass: repack W (fp32, row-major 128xK) into bf16 split fragment-linear image.
// f-chunk layout (16B units): [s in {hi,lo}][ksl][idx=mt*64+lane]
// element: W[o = mt*16+(l&15)][c = f*H + pass*64 + ksl*32 + (l>>4)*8 + j]
__global__ void repack_w_kernel(const float* __restrict__ W, unsigned short* __restrict__ dst,
                                int H, int NP, int KSP, int nchunks)
{
  const int t = blockIdx.x * 256 + threadIdx.x;
  if (t >= nchunks) return;
  const int K = 32 * H;
  const int cpf = NP * KSP * 512;
  const int f = t / cpf;
  int r = t % cpf;
  const int pass = r / (KSP * 512); r %= (KSP * 512);
  const int ksl = r / 512;
  const int idx = r % 512;
  const int mt = idx >> 6, l = idx & 63;
  const int o = mt * 16 + (l & 15);
  const int c = f * H + pass * 64 + ksl * 32 + (l >> 4) * 8;
  const float* s = W + (size_t)o * K + c;
  u16x4 h0, h1, l0, l1;
#pragma unroll
  for (int j = 0; j < 4; ++j) {
    float v = s[j];
    unsigned short hb = f2bf(v);
    h0[j] = hb; l0[j] = f2bf(v - bf2f(hb));
    v = s[4 + j];
    hb = f2bf(v);
    h1[j] = hb; l1[j] = f2bf(v - bf2f(hb));
  }
  const size_t chunk_hi = ((size_t)((f * NP + pass) * 2 + 0) * KSP + ksl) * 512 + idx;
  const size_t chunk_lo = ((size_t)((f * NP + pass) * 2 + 1) * KSP + ksl) * 512 + idx;
  *(u16x4*)(dst + chunk_hi * 8)     = h0;
  *(u16x4*)(dst + chunk_hi * 8 + 4) = h1;
  *(u16x4*)(dst + chunk_lo * 8)     = l0;
  *(u16x4*)(dst + chunk_lo * 8 + 4) = l1;
}

// ---- main layer kernel ----
// grid 256 blocks x 512 threads; block handles b0=2*blk, b0+1. Wave w owns o in [16w,16w+16).
// LDS: [0, 2*CHUNK) = W chunk double buffer; [2*CHUNK, +16KB) = raw x[b0], x[b0+1].
template<int H, int NPASS, int KSP, bool FIRST, bool STORE_H>
__global__ __launch_bounds__(512, 2) void cin_mfma_layer(
    const unsigned short* __restrict__ Wimg,
    const float* __restrict__ x,               // (B,32,64) fp32
    const unsigned short* __restrict__ hTin,   // hi plane; lo at +HT_LO  (null if FIRST)
    const float* __restrict__ bias,
    unsigned short* __restrict__ hTout,        // hi plane; lo at +HT_LO
    float* __restrict__ outs, int col_off)
{
  constexpr int CHUNK = 2 * KSP * 8192;        // bytes per f-chunk (hi+lo)
  constexpr int SR = 2 * KSP;                  // staging rounds per chunk
  constexpr int XOFF = 2 * CHUNK;
  __shared__ char lds[XOFF + 16384];
  const int tid = threadIdx.x;
  const int w = tid >> 6, l = tid & 63, g = l >> 4, li = l & 15;
  const int b0 = blockIdx.x * 2;
  const float* lx0 = (const float*)(lds + XOFF);
  const float* lx1 = (const float*)(lds + XOFF + 8192);

  // stage raw x[b0], x[b0+1] (2 x 8 KB, lane-linear)
#pragma unroll
  for (int r = 0; r < 2; ++r)
    gll16(x + (size_t)(b0 + r) * 2048 + tid * 4, lds + XOFF + r * 8192 + w * 1024);

  f32x4 Y0[4], Y1[4];
#pragma unroll
  for (int nt = 0; nt < 4; ++nt) {
    Y0[nt] = (f32x4){0.f, 0.f, 0.f, 0.f};
    Y1[nt] = (f32x4){0.f, 0.f, 0.f, 0.f};
  }
  const f32x4 zero4 = (f32x4){0.f, 0.f, 0.f, 0.f};

  bf16x8 Bh0[KSP][4], Bl0[KSP][4], Bh1[KSP][4], Bl1[KSP][4];
  int cur = 0;

  for (int pass = 0; pass < NPASS; ++pass) {
    if constexpr (!FIRST) {
      // B-fragments for this pass, both batches (reused across all 32 f)
#pragma unroll
      for (int ks = 0; ks < KSP; ++ks)
#pragma unroll
        for (int nt = 0; nt < 4; ++nt) {
          const size_t co = (size_t)(nt * 16 + li) * 128 + pass * 64 + ks * 32 + g * 8;
          const size_t o0 = (size_t)b0 * 8192 + co;
          const size_t o1 = (size_t)(b0 + 1) * 8192 + co;
          Bh0[ks][nt] = *(const bf16x8*)(hTin + o0);
          Bl0[ks][nt] = *(const bf16x8*)(hTin + HT_LO + o0);
          Bh1[ks][nt] = *(const bf16x8*)(hTin + o1);
          Bl1[ks][nt] = *(const bf16x8*)(hTin + HT_LO + o1);
        }
    }
    // stage W chunk (f=0, pass) into buf cur
    {
      const char* src = (const char*)Wimg + (size_t)(0 * NPASS + pass) * CHUNK;
#pragma unroll
      for (int r = 0; r < SR; ++r)
        gll16(src + (size_t)(r * 512 + tid) * 16,
              lds + cur * CHUNK + (r * 512 + w * 64) * 16);
    }
    if (pass == 0) {
      // the ONLY barrier: publishes the shared x-tiles to all waves
      asm volatile("s_waitcnt vmcnt(0)" ::: "memory");
      __builtin_amdgcn_s_barrier();
    }

    if constexpr (FIRST) {
      // build split B-fragments from raw x in LDS (h == x; NPASS==1, KSP==1)
#pragma unroll
      for (int nt = 0; nt < 4; ++nt) {
        union { bf16x8 v; unsigned short u[8]; } th0, tl0, th1, tl1;
#pragma unroll
        for (int j = 0; j < 8; ++j) {
          const float x0 = lx0[(g * 8 + j) * 64 + nt * 16 + li];
          const float x1 = lx1[(g * 8 + j) * 64 + nt * 16 + li];
          unsigned short hb = f2bf(x0);
          th0.u[j] = hb; tl0.u[j] = f2bf(x0 - bf2f(hb));
          hb = f2bf(x1);
          th1.u[j] = hb; tl1.u[j] = f2bf(x1 - bf2f(hb));
        }
        Bh0[0][nt] = th0.v; Bl0[0][nt] = tl0.v;
        Bh1[0][nt] = th1.v; Bl1[0][nt] = tl1.v;
      }
    }

    for (int f = 0; f < 32; ++f) {
      if (f < 31) {
        // prefetch W chunk for f+1 into the other buffer; counted per-wave wait
        const char* src = (const char*)Wimg + (size_t)((f + 1) * NPASS + pass) * CHUNK;
#pragma unroll
        for (int r = 0; r < SR; ++r)
          gll16(src + (size_t)(r * 512 + tid) * 16,
                lds + (cur ^ 1) * CHUNK + (r * 512 + w * 64) * 16);
        asm volatile("s_waitcnt vmcnt(%0)" :: "i"(SR) : "memory");
      } else {
        asm volatile("s_waitcnt vmcnt(0)" ::: "memory");
      }
      // NO barrier: wave w reads only the LDS bytes it staged itself.

      f32x4 G0[4], G1[4];
      __builtin_amdgcn_s_setprio(1);
#pragma unroll
      for (int ks = 0; ks < KSP; ++ks) {
        const bf16x8 Ah = *(const bf16x8*)(lds + cur * CHUNK + (((0 * KSP + ks) * 8 + w) * 64 + l) * 16);
        const bf16x8 Al = *(const bf16x8*)(lds + cur * CHUNK + (((1 * KSP + ks) * 8 + w) * 64 + l) * 16);
#pragma unroll
        for (int nt = 0; nt < 4; ++nt) {
          G0[nt] = __builtin_amdgcn_mfma_f32_16x16x32_bf16(Ah, Bh0[ks][nt],
                       (ks == 0) ? zero4 : G0[nt], 0, 0, 0);
          G1[nt] = __builtin_amdgcn_mfma_f32_16x16x32_bf16(Ah, Bh1[ks][nt],
                       (ks == 0) ? zero4 : G1[nt], 0, 0, 0);
          G0[nt] = __builtin_amdgcn_mfma_f32_16x16x32_bf16(Ah, Bl0[ks][nt], G0[nt], 0, 0, 0);
          G1[nt] = __builtin_amdgcn_mfma_f32_16x16x32_bf16(Ah, Bl1[ks][nt], G1[nt], 0, 0, 0);
          G0[nt] = __builtin_amdgcn_mfma_f32_16x16x32_bf16(Al, Bh0[ks][nt], G0[nt], 0, 0, 0);
          G1[nt] = __builtin_amdgcn_mfma_f32_16x16x32_bf16(Al, Bh1[ks][nt], G1[nt], 0, 0, 0);
        }
      }
      __builtin_amdgcn_s_setprio(0);
#pragma unroll
      for (int nt = 0; nt < 4; ++nt) {
        const float s0 = lx0[f * 64 + nt * 16 + li];   // fp32 x-scales (broadcast reads)
        const float s1 = lx1[f * 64 + nt * 16 + li];
        Y0[nt] += G0[nt] * s0;
        Y1[nt] += G1[nt] * s1;
      }
      cur ^= 1;
    }
  }

  // ---- epilogue: bias, split-hT stores, outs row-sums (both batches) ----
  const f32x4 bv = *(const f32x4*)(bias + w * 16 + g * 4);
#pragma unroll
  for (int nt = 0; nt < 4; ++nt) { Y0[nt] += bv; Y1[nt] += bv; }

  if constexpr (STORE_H) {
#pragma unroll
    for (int nt = 0; nt < 4; ++nt) {
      const int d = nt * 16 + li;
      u16x4 ph0, pl0, ph1, pl1;
#pragma unroll
      for (int j = 0; j < 4; ++j) {
        unsigned short hb = f2bf(Y0[nt][j]);
        ph0[j] = hb; pl0[j] = f2bf(Y0[nt][j] - bf2f(hb));
        hb = f2bf(Y1[nt][j]);
        ph1[j] = hb; pl1[j] = f2bf(Y1[nt][j] - bf2f(hb));
      }
      const size_t co = (size_t)d * 128 + w * 16 + g * 4;
      const size_t o0 = (size_t)b0 * 8192 + co;
      const size_t o1 = (size_t)(b0 + 1) * 8192 + co;
      *(u16x4*)(hTout + o0)         = ph0;
      *(u16x4*)(hTout + HT_LO + o0) = pl0;
      *(u16x4*)(hTout + o1)         = ph1;
      *(u16x4*)(hTout + HT_LO + o1) = pl1;
    }
  }

  {
    f32x4 s0 = Y0[0] + Y0[1] + Y0[2] + Y0[3];
    f32x4 s1 = Y1[0] + Y1[1] + Y1[2] + Y1[3];
#pragma unroll
    for (int m = 1; m < 16; m <<= 1) {
      s0.x += __shfl_xor(s0.x, m, 16); s0.y += __shfl_xor(s0.y, m, 16);
      s0.z += __shfl_xor(s0.z, m, 16); s0.w += __shfl_xor(s0.w, m, 16);
      s1.x += __shfl_xor(s1.x, m, 16); s1.y += __shfl_xor(s1.y, m, 16);
      s1.z += __shfl_xor(s1.z, m, 16); s1.w += __shfl_xor(s1.w, m, 16);
    }
    if (li == 0) {
      *(f32x4*)(outs + (size_t)b0 * 384 + col_off + w * 16 + g * 4)       = s0;
      *(f32x4*)(outs + (size_t)(b0 + 1) * 384 + col_off + w * 16 + g * 4) = s1;
    }
  }
}

// ---- final: out[b] = sigmoid( relu(outs[b,:]) . Wout + bout ) ----
__global__ __launch_bounds__(64) void cin_final_kernel(
    const float* __restrict__ outs, const float* __restrict__ Wout,
    const float* __restrict__ bout, float* __restrict__ out)
{
  const int b = blockIdx.x;
  const int lane = threadIdx.x;
  float p = 0.f;
  for (int j = lane; j < 384; j += 64) {
    float v = outs[(size_t)b * 384 + j];
    v = v > 0.f ? v : 0.f;
    p = fmaf(v, Wout[j], p);
  }
#pragma unroll
  for (int m = 32; m; m >>= 1) p += __shfl_xor(p, m, 64);
  if (lane == 0) {
    const float t = p + bout[0];
    out[b] = 1.f / (1.f + expf(-t));
  }
}

extern "C" void kernel_launch(void* const* d_in, const int* in_sizes, int n_in,
                              void* d_out, int out_size, void* d_ws, size_t ws_size,
                              hipStream_t stream)
{
  const float* x    = (const float*)d_in[0];
  const float* W0   = (const float*)d_in[1];
  const float* b0   = (const float*)d_in[2];
  const float* W1   = (const float*)d_in[3];
  const float* b1   = (const float*)d_in[4];
  const float* W2   = (const float*)d_in[5];
  const float* b2   = (const float*)d_in[6];
  const float* Wout = (const float*)d_in[7];
  const float* bout = (const float*)d_in[8];
  float* out = (float*)d_out;

  char* ws = (char*)d_ws;
  unsigned short* hT1  = (unsigned short*)ws;                    // 16 MB (hi+lo)
  unsigned short* hT2  = (unsigned short*)(ws + (16 << 20));     // 16 MB
  float*          outs = (float*)        (ws + (32 << 20));      // 768 KB
  unsigned short* Wi0  = (unsigned short*)(ws + (33 << 20));               // 512 KB
  unsigned short* Wi1  = (unsigned short*)(ws + (33 << 20) + (1 << 19));   // 2 MB
  unsigned short* Wi2  = (unsigned short*)(ws + (33 << 20) + (1 << 19) + (2 << 20)); // 2 MB

  repack_w_kernel<<<64,  256, 0, stream>>>(W0, Wi0, 32,  1, 1, 16384);
  repack_w_kernel<<<256, 256, 0, stream>>>(W1, Wi1, 128, 2, 2, 65536);
  repack_w_kernel<<<256, 256, 0, stream>>>(W2, Wi2, 128, 2, 2, 65536);

  cin_mfma_layer<32,  1, 1, true,  true ><<<256, 512, 0, stream>>>(Wi0, x, nullptr, b0, hT1, outs, 0);
  cin_mfma_layer<128, 2, 2, false, true ><<<256, 512, 0, stream>>>(Wi1, x, hT1,    b1, hT2, outs, 128);
  cin_mfma_layer<128, 2, 2, false, false><<<256, 512, 0, stream>>>(Wi2, x, hT2,    b2, nullptr, outs, 256);

  cin_final_kernel<<<512, 64, 0, stream>>>(outs, Wout, bout, out);
}

// Round 9
// 194.549 us; speedup vs baseline: 1.3195x; 1.0275x over previous
//
#include <hip/hip_runtime.h>
#include <math.h>

// CIN (xDeepFM) — split-bf16 16x16x32 MFMA, 2 batches/block, 3-deep prefetch.
// y[b,o,d] = bias[o] + sum_f x[b,f,d] * ( sum_h W[o,f*H+h] * h_in[b,h,d] )
//   W*h ~= Whi*hhi + Whi*hlo + Wlo*hhi   (split bf16, lo*lo dropped)
// Pipeline: 4 LDS chunk buffers; at iteration c prefetch chunk c+3 and wait
// vmcnt(3*SR) (never 0 mid-loop) -> ~3 periods of load-latency tolerance.
// Wave w stages and reads ONLY its own 1KB slice of each staging round ->
// no hot-loop barriers (one prologue barrier publishes the x-tiles).
// W image is chunk-sequential in iteration order c = pass*32 + f.
// B=512, F=32, D=64, O=128; H0=32 (h=x), H1=H2=128.

typedef __attribute__((ext_vector_type(8))) short bf16x8;
typedef __attribute__((ext_vector_type(4))) float f32x4;
typedef __attribute__((ext_vector_type(4))) unsigned short u16x4;

#define HT_LO 4194304   // shorts: 512*64*128 (offset of lo plane)

__device__ __forceinline__ unsigned short f2bf(float f) {
  unsigned int u = __float_as_uint(f);
  u = (u + 0x7fffu + ((u >> 16) & 1u)) >> 16;   // RNE
  return (unsigned short)u;
}
__device__ __forceinline__ float bf2f(unsigned short h) {
  return __uint_as_float((unsigned int)h << 16);
}

__device__ __forceinline__ void gll16(const void* g, void* l) {
  __builtin_amdgcn_global_load_lds(
      (const __attribute__((address_space(1))) unsigned int*)g,
      (__attribute__((address_space(3))) unsigned int*)l, 16, 0, 0);
}

// ---- pre-pass: repack W (fp32, row-major 128xK) into split-bf16 image,
// chunk-sequential in ITERATION order: chunk c = pass*32 + f at offset c*CHUNK.
// in-chunk (16B units): [s in {hi,lo}][ksl][idx = mt*64 + lane]  (same as r8)
// element: W[o = mt*16+(l&15)][kcol = f*H + pass*(KSP*32) + ksl*32 + (l>>4)*8 + j]
__global__ void repack_w_kernel(const float* __restrict__ W, unsigned short* __restrict__ dst,
                                int H, int KSP, int nthreads)
{
  const int t = blockIdx.x * 256 + threadIdx.x;
  if (t >= nthreads) return;
  const int K = 32 * H;
  const int idx = t & 511;
  const int ksl = (t >> 9) % KSP;
  const int c   = (t >> 9) / KSP;
  const int pass = c >> 5, f = c & 31;
  const int mt = idx >> 6, l = idx & 63;
  const int o = mt * 16 + (l & 15);
  const int kcol = f * H + pass * (KSP * 32) + ksl * 32 + (l >> 4) * 8;
  const float* s = W + (size_t)o * K + kcol;
  u16x4 h0, h1, l0, l1;
#pragma unroll
  for (int j = 0; j < 4; ++j) {
    float v = s[j];
    unsigned short hb = f2bf(v);
    h0[j] = hb; l0[j] = f2bf(v - bf2f(hb));
    v = s[4 + j];
    hb = f2bf(v);
    h1[j] = hb; l1[j] = f2bf(v - bf2f(hb));
  }
  const size_t CU16 = (size_t)2 * KSP * 512;       // 16B units per chunk
  const size_t uhi = (size_t)c * CU16 + (size_t)(0 * KSP + ksl) * 512 + idx;
  const size_t ulo = (size_t)c * CU16 + (size_t)(1 * KSP + ksl) * 512 + idx;
  *(u16x4*)(dst + uhi * 8)     = h0;
  *(u16x4*)(dst + uhi * 8 + 4) = h1;
  *(u16x4*)(dst + ulo * 8)     = l0;
  *(u16x4*)(dst + ulo * 8 + 4) = l1;
}

// one pipeline stage: optional prefetch of chunk (C)+3, counted wait, consume chunk (C)
#define BODY(C, BUF, DOPREF, WAITN)                                                        \
  {                                                                                        \
    if (DOPREF) {                                                                          \
      const char* psrc = (const char*)Wimg + (size_t)((C) + 3) * CHUNK;                    \
      _Pragma("unroll")                                                                    \
      for (int r = 0; r < SR; ++r)                                                         \
        gll16(psrc + (size_t)(r * 512 + tid) * 16,                                         \
              lds + (((BUF) + 3) & 3) * CHUNK + (r * 512 + w * 64) * 16);                  \
    }                                                                                      \
    asm volatile("s_waitcnt vmcnt(%0)" :: "i"(WAITN) : "memory");                          \
    const char* bufb = lds + (BUF) * CHUNK;                                                \
    f32x4 G0[4], G1[4];                                                                    \
    __builtin_amdgcn_s_setprio(1);                                                         \
    _Pragma("unroll")                                                                      \
    for (int ks = 0; ks < KSP; ++ks) {                                                     \
      const bf16x8 Ah = *(const bf16x8*)(bufb + (((0 * KSP + ks) * 8 + w) * 64 + l) * 16); \
      const bf16x8 Al = *(const bf16x8*)(bufb + (((1 * KSP + ks) * 8 + w) * 64 + l) * 16); \
      _Pragma("unroll")                                                                    \
      for (int nt = 0; nt < 4; ++nt) {                                                     \
        G0[nt] = __builtin_amdgcn_mfma_f32_16x16x32_bf16(Ah, Bh0[ks][nt],                  \
                     (ks == 0) ? zero4 : G0[nt], 0, 0, 0);                                 \
        G1[nt] = __builtin_amdgcn_mfma_f32_16x16x32_bf16(Ah, Bh1[ks][nt],                  \
                     (ks == 0) ? zero4 : G1[nt], 0, 0, 0);                                 \
        G0[nt] = __builtin_amdgcn_mfma_f32_16x16x32_bf16(Ah, Bl0[ks][nt], G0[nt], 0, 0, 0);\
        G1[nt] = __builtin_amdgcn_mfma_f32_16x16x32_bf16(Ah, Bl1[ks][nt], G1[nt], 0, 0, 0);\
        G0[nt] = __builtin_amdgcn_mfma_f32_16x16x32_bf16(Al, Bh0[ks][nt], G0[nt], 0, 0, 0);\
        G1[nt] = __builtin_amdgcn_mfma_f32_16x16x32_bf16(Al, Bh1[ks][nt], G1[nt], 0, 0, 0);\
      }                                                                                    \
    }                                                                                      \
    __builtin_amdgcn_s_setprio(0);                                                         \
    const int f_ = (C) & 31;                                                               \
    _Pragma("unroll")                                                                      \
    for (int nt = 0; nt < 4; ++nt) {                                                       \
      const float s0 = lx0[f_ * 64 + nt * 16 + li];                                        \
      const float s1 = lx1[f_ * 64 + nt * 16 + li];                                        \
      Y0[nt] += G0[nt] * s0;                                                               \
      Y1[nt] += G1[nt] * s1;                                                               \
    }                                                                                      \
  }

// ---- main layer kernel ----
// grid 256 x 512 threads; block handles b0=2*blk, b0+1. Wave w owns o in [16w,16w+16).
// LDS: [0, 4*CHUNK) = 4-buffer chunk ring; [4*CHUNK, +16KB) = raw x[b0], x[b0+1].
template<int H, int NPASS, int KSP, bool FIRST, bool STORE_H>
__global__ __launch_bounds__(512, 2) void cin_mfma_layer(
    const unsigned short* __restrict__ Wimg,
    const float* __restrict__ x,               // (B,32,64) fp32
    const unsigned short* __restrict__ hTin,   // hi plane; lo at +HT_LO  (null if FIRST)
    const float* __restrict__ bias,
    unsigned short* __restrict__ hTout,        // hi plane; lo at +HT_LO
    float* __restrict__ outs, int col_off)
{
  constexpr int CHUNK = 2 * KSP * 8192;        // bytes per chunk (hi+lo)
  constexpr int SR = 2 * KSP;                  // gll rounds per chunk
  constexpr int NIT = NPASS * 32;
  constexpr int XOFF = 4 * CHUNK;
  __shared__ char lds[XOFF + 16384];
  const int tid = threadIdx.x;
  const int w = tid >> 6, l = tid & 63, g = l >> 4, li = l & 15;
  const int b0 = blockIdx.x * 2;
  const float* lx0 = (const float*)(lds + XOFF);
  const float* lx1 = (const float*)(lds + XOFF + 8192);

  // prologue: stage x[b0], x[b0+1] (2 gll) + chunks 0,1,2 (3*SR gll)
#pragma unroll
  for (int r = 0; r < 2; ++r)
    gll16(x + (size_t)(b0 + r) * 2048 + tid * 4, lds + XOFF + r * 8192 + w * 1024);
#pragma unroll
  for (int c = 0; c < 3; ++c) {
    const char* src = (const char*)Wimg + (size_t)c * CHUNK;
#pragma unroll
    for (int r = 0; r < SR; ++r)
      gll16(src + (size_t)(r * 512 + tid) * 16,
            lds + c * CHUNK + (r * 512 + w * 64) * 16);
  }

  f32x4 Y0[4], Y1[4];
#pragma unroll
  for (int nt = 0; nt < 4; ++nt) {
    Y0[nt] = (f32x4){0.f, 0.f, 0.f, 0.f};
    Y1[nt] = (f32x4){0.f, 0.f, 0.f, 0.f};
  }
  const f32x4 zero4 = (f32x4){0.f, 0.f, 0.f, 0.f};
  bf16x8 Bh0[KSP][4], Bl0[KSP][4], Bh1[KSP][4], Bl1[KSP][4];

  // the ONLY barrier: x-tiles (oldest 2 loads) complete -> publish to all waves
  asm volatile("s_waitcnt vmcnt(%0)" :: "i"(3 * SR) : "memory");
  __builtin_amdgcn_s_barrier();

  if constexpr (FIRST) {
    // build split B-fragments from raw x in LDS (h == x; NPASS==1, KSP==1)
#pragma unroll
    for (int nt = 0; nt < 4; ++nt) {
      union { bf16x8 v; unsigned short u[8]; } th0, tl0, th1, tl1;
#pragma unroll
      for (int j = 0; j < 8; ++j) {
        const float x0 = lx0[(g * 8 + j) * 64 + nt * 16 + li];
        const float x1 = lx1[(g * 8 + j) * 64 + nt * 16 + li];
        unsigned short hb = f2bf(x0);
        th0.u[j] = hb; tl0.u[j] = f2bf(x0 - bf2f(hb));
        hb = f2bf(x1);
        th1.u[j] = hb; tl1.u[j] = f2bf(x1 - bf2f(hb));
      }
      Bh0[0][nt] = th0.v; Bl0[0][nt] = tl0.v;
      Bh1[0][nt] = th1.v; Bl1[0][nt] = tl1.v;
    }
  }

  for (int pass = 0; pass < NPASS; ++pass) {
    if constexpr (!FIRST) {
      // B-fragments for this pass, both batches (reused across all 32 f)
#pragma unroll
      for (int ks = 0; ks < KSP; ++ks)
#pragma unroll
        for (int nt = 0; nt < 4; ++nt) {
          const size_t co = (size_t)(nt * 16 + li) * 128 + pass * (KSP * 32) + ks * 32 + g * 8;
          const size_t o0 = (size_t)b0 * 8192 + co;
          const size_t o1 = (size_t)(b0 + 1) * 8192 + co;
          Bh0[ks][nt] = *(const bf16x8*)(hTin + o0);
          Bl0[ks][nt] = *(const bf16x8*)(hTin + HT_LO + o0);
          Bh1[ks][nt] = *(const bf16x8*)(hTin + o1);
          Bl1[ks][nt] = *(const bf16x8*)(hTin + HT_LO + o1);
        }
    }
    const int cb = pass * 32;
    const int fomax = (pass == NPASS - 1) ? 28 : 32;
#pragma unroll 1
    for (int fo = 0; fo < fomax; fo += 4) {
      BODY(cb + fo + 0, 0, true, 3 * SR)
      BODY(cb + fo + 1, 1, true, 3 * SR)
      BODY(cb + fo + 2, 2, true, 3 * SR)
      BODY(cb + fo + 3, 3, true, 3 * SR)
    }
  }
  // tail: last 4 chunks; drain counts 3SR -> 2SR -> SR -> 0
  BODY(NIT - 4, 0, true,  3 * SR)   // issues chunk NIT-1 into buf 3
  BODY(NIT - 3, 1, false, 2 * SR)
  BODY(NIT - 2, 2, false, 1 * SR)
  BODY(NIT - 1, 3, false, 0)

  // ---- epilogue: bias, split-hT stores, outs row-sums (both batches) ----
  const f32x4 bv = *(const f32x4*)(bias + w * 16 + g * 4);
#pragma unroll
  for (int nt = 0; nt < 4; ++nt) { Y0[nt] += bv; Y1[nt] += bv; }

  if constexpr (STORE_H) {
#pragma unroll
    for (int nt = 0; nt < 4; ++nt) {
      const int d = nt * 16 + li;
      u16x4 ph0, pl0, ph1, pl1;
#pragma unroll
      for (int j = 0; j < 4; ++j) {
        unsigned short hb = f2bf(Y0[nt][j]);
        ph0[j] = hb; pl0[j] = f2bf(Y0[nt][j] - bf2f(hb));
        hb = f2bf(Y1[nt][j]);
        ph1[j] = hb; pl1[j] = f2bf(Y1[nt][j] - bf2f(hb));
      }
      const size_t co = (size_t)d * 128 + w * 16 + g * 4;
      const size_t o0 = (size_t)b0 * 8192 + co;
      const size_t o1 = (size_t)(b0 + 1) * 8192 + co;
      *(u16x4*)(hTout + o0)         = ph0;
      *(u16x4*)(hTout + HT_LO + o0) = pl0;
      *(u16x4*)(hTout + o1)         = ph1;
      *(u16x4*)(hTout + HT_LO + o1) = pl1;
    }
  }

  {
    f32x4 s0 = Y0[0] + Y0[1] + Y0[2] + Y0[3];
    f32x4 s1 = Y1[0] + Y1[1] + Y1[2] + Y1[3];
#pragma unroll
    for (int m = 1; m < 16; m <<= 1) {
      s0.x += __shfl_xor(s0.x, m, 16); s0.y += __shfl_xor(s0.y, m, 16);
      s0.z += __shfl_xor(s0.z, m, 16); s0.w += __shfl_xor(s0.w, m, 16);
      s1.x += __shfl_xor(s1.x, m, 16); s1.y += __shfl_xor(s1.y, m, 16);
      s1.z += __shfl_xor(s1.z, m, 16); s1.w += __shfl_xor(s1.w, m, 16);
    }
    if (li == 0) {
      *(f32x4*)(outs + (size_t)b0 * 384 + col_off + w * 16 + g * 4)       = s0;
      *(f32x4*)(outs + (size_t)(b0 + 1) * 384 + col_off + w * 16 + g * 4) = s1;
    }
  }
}

// ---- final: out[b] = sigmoid( relu(outs[b,:]) . Wout + bout ) ----
__global__ __launch_bounds__(64) void cin_final_kernel(
    const float* __restrict__ outs, const float* __restrict__ Wout,
    const float* __restrict__ bout, float* __restrict__ out)
{
  const int b = blockIdx.x;
  const int lane = threadIdx.x;
  float p = 0.f;
  for (int j = lane; j < 384; j += 64) {
    float v = outs[(size_t)b * 384 + j];
    v = v > 0.f ? v : 0.f;
    p = fmaf(v, Wout[j], p);
  }
#pragma unroll
  for (int m = 32; m; m >>= 1) p += __shfl_xor(p, m, 64);
  if (lane == 0) {
    const float t = p + bout[0];
    out[b] = 1.f / (1.f + expf(-t));
  }
}

extern "C" void kernel_launch(void* const* d_in, const int* in_sizes, int n_in,
                              void* d_out, int out_size, void* d_ws, size_t ws_size,
                              hipStream_t stream)
{
  const float* x    = (const float*)d_in[0];
  const float* W0   = (const float*)d_in[1];
  const float* b0   = (const float*)d_in[2];
  const float* W1   = (const float*)d_in[3];
  const float* b1   = (const float*)d_in[4];
  const float* W2   = (const float*)d_in[5];
  const float* b2   = (const float*)d_in[6];
  const float* Wout = (const float*)d_in[7];
  const float* bout = (const float*)d_in[8];
  float* out = (float*)d_out;

  char* ws = (char*)d_ws;
  unsigned short* hT1  = (unsigned short*)ws;                    // 16 MB (hi+lo)
  unsigned short* hT2  = (unsigned short*)(ws + (16 << 20));     // 16 MB
  float*          outs = (float*)        (ws + (32 << 20));      // 768 KB
  unsigned short* Wi0  = (unsigned short*)(ws + (33 << 20));               // 512 KB
  unsigned short* Wi1  = (unsigned short*)(ws + (33 << 20) + (1 << 19));   // 2 MB
  unsigned short* Wi2  = (unsigned short*)(ws + (33 << 20) + (1 << 19) + (2 << 20)); // 2 MB

  // nthreads = (#chunks) * KSP * 512 = K/32 * 512
  repack_w_kernel<<<64,  256, 0, stream>>>(W0, Wi0, 32,  1, 16384);
  repack_w_kernel<<<256, 256, 0, stream>>>(W1, Wi1, 128, 2, 65536);
  repack_w_kernel<<<256, 256, 0, stream>>>(W2, Wi2, 128, 2, 65536);

  cin_mfma_layer<32,  1, 1, true,  true ><<<256, 512, 0, stream>>>(Wi0, x, nullptr, b0, hT1, outs, 0);
  cin_mfma_layer<128, 2, 2, false, true ><<<256, 512, 0, stream>>>(Wi1, x, hT1,    b1, hT2, outs, 128);
  cin_mfma_layer<128, 2, 2, false, false><<<256, 512, 0, stream>>>(Wi2, x, hT2,    b2, nullptr, outs, 256);

  cin_final_kernel<<<512, 64, 0, stream>>>(outs, Wout, bout, out);
}